// Round 10
// baseline (10286.646 us; speedup 1.0000x reference)
//
#include <hip/hip_runtime.h>

#define T_STEPS 512
#define BATCH   64
#define EDIM    256
#define HDIM    512
#define HB      (BATCH * HDIM)          // uints per h-state slot (32768)
#define NL      18                      // k-slices cached in LDS (per WG): 18*8KB = 144KB
#define NWG     256

typedef __attribute__((ext_vector_type(8))) short  bf16x8;
typedef __attribute__((ext_vector_type(4))) float  f32x4;
typedef unsigned short ushort_t;
typedef unsigned int   uint_t;

// ---------- bf16 helpers ----------
__device__ __forceinline__ unsigned short f2bf(float x) {
    unsigned u = __float_as_uint(x);
    u += 0x7fffu + ((u >> 16) & 1u);
    return (unsigned short)(u >> 16);
}
__device__ __forceinline__ float bf2f(unsigned short h) {
    return __uint_as_float(((unsigned)h) << 16);
}

// ---------- activations ----------
__device__ __forceinline__ float sigm(float x) {
    x = fminf(fmaxf(x, -30.f), 30.f);
    return 1.f / (1.f + __expf(-x));
}
__device__ __forceinline__ float tanh_f(float x) {
    x = fminf(fmaxf(x, -15.f), 15.f);
    float e = __expf(2.f * x);
    return (e - 1.f) / (e + 1.f);
}

// ---------- workspace byte offsets ----------
#define BYTE_XEHI   ((size_t)0)          // ushort[512*64*256] = 16,777,216 B
#define BYTE_HC0    ((size_t)16777216)   // uint[2*HB]
#define BYTE_HC1    ((size_t)17039360)   // uint[2*HB]
#define BYTE_B0HI   ((size_t)17301760)
#define BYTE_B0LO   ((size_t)20447488)
#define BYTE_B1HI   ((size_t)23593216)
#define BYTE_B1LO   ((size_t)27787520)   // end 31,981,824
#define BYTE_BAR    ((size_t)31981824)   // uint[1024]: 16 L1 ctrs + L2 ctr + flag (128B stride)

// ---------- prep: gather embeddings -> bf16 row-major [t][b][256] ----------
__global__ __launch_bounds__(256) void xepack_kernel(const int* __restrict__ x,
                                                     const float* __restrict__ emb,
                                                     ushort_t* __restrict__ XeHi) {
    int tid = blockIdx.x * 256 + threadIdx.x;          // 1,048,576 threads
    int c8 = tid & 31;
    int b  = (tid >> 5) & 63;
    int t  = tid >> 11;
    int idx = x[b * T_STEPS + t];
    const float4* e = (const float4*)(emb + (size_t)idx * EDIM + c8 * 8);
    float4 f0 = e[0], f1 = e[1];
    ushort_t v[8];
    v[0] = f2bf(f0.x); v[1] = f2bf(f0.y); v[2] = f2bf(f0.z); v[3] = f2bf(f0.w);
    v[4] = f2bf(f1.x); v[5] = f2bf(f1.y); v[6] = f2bf(f1.z); v[7] = f2bf(f1.w);
    ushort_t* dst = XeHi + ((size_t)t * BATCH + b) * EDIM + c8 * 8;
    *(uint4*)dst = *(uint4*)v;
}

// ---------- prep: pack weights into B-fragment order, bf16 hi/lo pair ----------
__global__ __launch_bounds__(256) void wpack_kernel(const float* __restrict__ Wih0, const float* __restrict__ Whh0,
                                                    const float* __restrict__ Wih1, const float* __restrict__ Whh1,
                                                    ushort_t* __restrict__ B0hi, ushort_t* __restrict__ B0lo,
                                                    ushort_t* __restrict__ B1hi, ushort_t* __restrict__ B1lo) {
    const int NT0 = 32 * 4 * 24 * 64;   // 196608
    const int NT1 = 32 * 4 * 32 * 64;   // 262144
    int tid = blockIdx.x * 256 + threadIdx.x;
    if (tid >= NT0 + NT1) return;
    int layer, idx, KS;
    ushort_t *dhi, *dlo;
    if (tid < NT0) { layer = 0; idx = tid;        KS = 24; dhi = B0hi; dlo = B0lo; }
    else           { layer = 1; idx = tid - NT0;  KS = 32; dhi = B1hi; dlo = B1lo; }
    int lane = idx & 63;
    int t1 = idx >> 6;
    int ks = t1 % KS;
    int t2 = t1 / KS;
    int g = t2 & 3;
    int u = t2 >> 2;
    int n = g * HDIM + u * 16 + (lane & 15);
    int k = ks * 32 + (lane >> 4) * 8;
    const float* src;
    if (layer == 0) src = (k < EDIM) ? (Wih0 + (size_t)n * EDIM + k) : (Whh0 + (size_t)n * HDIM + (k - EDIM));
    else            src = (k < HDIM) ? (Wih1 + (size_t)n * HDIM + k) : (Whh1 + (size_t)n * HDIM + (k - HDIM));
    const float4* s4 = (const float4*)src;
    float4 f0 = s4[0], f1 = s4[1];
    float f[8] = {f0.x, f0.y, f0.z, f0.w, f1.x, f1.y, f1.z, f1.w};
    ushort_t vh[8], vl[8];
    #pragma unroll
    for (int j = 0; j < 8; ++j) {
        vh[j] = f2bf(f[j]);
        vl[j] = f2bf(f[j] - bf2f(vh[j]));
    }
    *(uint4*)(dhi + (size_t)idx * 8) = *(uint4*)vh;
    *(uint4*)(dlo + (size_t)idx * 8) = *(uint4*)vl;
}

// ---------- prep: zero ----------
__global__ void zero_kernel(uint_t* __restrict__ p, int n) {
    int i = blockIdx.x * blockDim.x + threadIdx.x;
    if (i < n) p[i] = 0u;
}

// ---------- two-level tree grid barrier (agent scope, LLC) ----------
__device__ __forceinline__ void gridbar(uint_t* bar, unsigned tgt) {
    __syncthreads();   // drains all WG vmem stores before arrival
    if (threadIdx.x == 0) {
        uint_t* c1 = bar + (size_t)(blockIdx.x & 15) * 32;
        uint_t* c2 = bar + (size_t)16 * 32;
        uint_t* fl = bar + (size_t)17 * 32;
        unsigned o = __hip_atomic_fetch_add(c1, 1u, __ATOMIC_ACQ_REL, __HIP_MEMORY_SCOPE_AGENT);
        if (o == tgt * 16u - 1u) {
            unsigned o2 = __hip_atomic_fetch_add(c2, 1u, __ATOMIC_ACQ_REL, __HIP_MEMORY_SCOPE_AGENT);
            if (o2 == tgt * 16u - 1u)
                __hip_atomic_store(fl, tgt, __ATOMIC_RELEASE, __HIP_MEMORY_SCOPE_AGENT);
        }
        while (__hip_atomic_load(fl, __ATOMIC_RELAXED, __HIP_MEMORY_SCOPE_AGENT) < tgt) {}
        (void)__hip_atomic_load(fl, __ATOMIC_ACQUIRE, __HIP_MEMORY_SCOPE_AGENT);
    }
    __syncthreads();
}

// ---------- load 8 packed h-values (hi|lo) as two bf16x8 fragments ----------
__device__ __forceinline__ void loadH8(const uint_t* q, bf16x8& hi, bf16x8& lo) {
    unsigned long long a0 = __hip_atomic_load((const unsigned long long*)(q + 0), __ATOMIC_RELAXED, __HIP_MEMORY_SCOPE_AGENT);
    unsigned long long a1 = __hip_atomic_load((const unsigned long long*)(q + 2), __ATOMIC_RELAXED, __HIP_MEMORY_SCOPE_AGENT);
    unsigned long long a2 = __hip_atomic_load((const unsigned long long*)(q + 4), __ATOMIC_RELAXED, __HIP_MEMORY_SCOPE_AGENT);
    unsigned long long a3 = __hip_atomic_load((const unsigned long long*)(q + 6), __ATOMIC_RELAXED, __HIP_MEMORY_SCOPE_AGENT);
    unsigned u0 = (unsigned)a0, u1 = (unsigned)(a0 >> 32);
    unsigned u2 = (unsigned)a1, u3 = (unsigned)(a1 >> 32);
    unsigned u4 = (unsigned)a2, u5 = (unsigned)(a2 >> 32);
    unsigned u6 = (unsigned)a3, u7 = (unsigned)(a3 >> 32);
    union { bf16x8 v; unsigned u[4]; } H, L;
    H.u[0] = __builtin_amdgcn_perm(u1, u0, 0x05040100u);
    L.u[0] = __builtin_amdgcn_perm(u1, u0, 0x07060302u);
    H.u[1] = __builtin_amdgcn_perm(u3, u2, 0x05040100u);
    L.u[1] = __builtin_amdgcn_perm(u3, u2, 0x07060302u);
    H.u[2] = __builtin_amdgcn_perm(u5, u4, 0x05040100u);
    L.u[2] = __builtin_amdgcn_perm(u5, u4, 0x07060302u);
    H.u[3] = __builtin_amdgcn_perm(u7, u6, 0x05040100u);
    L.u[3] = __builtin_amdgcn_perm(u7, u6, 0x07060302u);
    hi = H.v; lo = L.v;
}

#define MFMA __builtin_amdgcn_mfma_f32_16x16x32_bf16

// ---------- main persistent cooperative kernel (round-6 data path) ----------
// 256 WGs x 128 threads (2 waves). WG w: layer = w>>7; u=(w>>2)&31; bt=w&3.
__global__ __launch_bounds__(128, 1) void lstm_main(
    const ushort_t* __restrict__ XeHi,
    uint_t* __restrict__ Hc0, uint_t* __restrict__ Hc1,
    uint_t* __restrict__ bar,
    const ushort_t* __restrict__ B0hi, const ushort_t* __restrict__ B0lo,
    const ushort_t* __restrict__ B1hi, const ushort_t* __restrict__ B1lo,
    const float* __restrict__ bias0, const float* __restrict__ bias1,
    const float* __restrict__ Wclf, const float* __restrict__ bclf,
    float* __restrict__ out)
{
    __shared__ float red[4][4][64];
    __shared__ ushort_t wlds[NL * 8 * 512];   // 144KB weight cache

    const int lane = threadIdx.x & 63;
    const int wv   = threadIdx.x >> 6;          // 0 or 1
    const int wg   = blockIdx.x;
    const int layer = wg >> 7;
    const int rr   = wg & 127;
    const int u    = rr >> 2;
    const int bt   = rr & 3;
    const int KS   = layer ? 32 : 24;
    const ushort_t* Bhi = layer ? B1hi : B0hi;
    const ushort_t* Blo = layer ? B1lo : B0lo;
    const float* bias   = layer ? bias1 : bias0;

    // per-wave k-slice schedule: nc cached + nr residual
    const int nc   = NL / 2;                            // 9
    const int cBeg = wv ? NL / 2 : 0;
    const int rBeg = NL + (wv ? (KS - NL) / 2 : 0);
    const int nr   = (KS - NL) / 2;                     // 3 (L0) or 7 (L1)
    const int n    = nc + nr;

    // hoisted per-lane constants
    const int rowA = bt * 16 + (lane & 15);     // batch row for A-frags
    const int koffA = (lane >> 4) * 8;
    const size_t gs    = (size_t)KS * 512;      // gate stride in packed B
    const size_t bBase = (size_t)(u * 4) * gs + (size_t)lane * 8;
    float bg0 = bias[0 * HDIM + u * 16 + (lane & 15)];
    float bg1 = bias[1 * HDIM + u * 16 + (lane & 15)];
    float bg2 = bias[2 * HDIM + u * 16 + (lane & 15)];
    float bg3 = bias[3 * HDIM + u * 16 + (lane & 15)];

    // ---- stage weight k-slices [0, NL) into LDS (once) ----
    for (int fid = wv; fid < NL * 8; fid += 2) {
        int ks  = fid >> 3;
        int buf = (fid >> 2) & 1;
        int g   = fid & 3;
        const ushort_t* src = (buf ? Blo : Bhi) + bBase + (size_t)g * gs + (size_t)ks * 512;
        *(bf16x8*)(wlds + (size_t)fid * 512 + lane * 8) = *(const bf16x8*)src;
    }
    __syncthreads();

    f32x4 cst = {0.f, 0.f, 0.f, 0.f};           // persistent c-state (owner wave)

    for (int p = 0; p <= T_STEPS; ++p) {
        const bool active = layer ? (p >= 1) : (p < T_STEPS);
        f32x4 acc0 = {0,0,0,0}, acc1 = {0,0,0,0}, acc2 = {0,0,0,0}, acc3 = {0,0,0,0};

        if (active) {
            auto ksOf = [&](int i) { return (i < nc) ? (cBeg + i) : (rBeg + (i - nc)); };
            // ---- A fragments: XeHi plain, h-state via agent-scope LLC loads ----
            auto loadA = [&](int ks, bf16x8& ah, bf16x8& al, int& haslo) {
                if (layer == 0 && ks < 8) {
                    const ushort_t* hi = XeHi + (size_t)p * (BATCH * EDIM);
                    ah = *(const bf16x8*)(hi + (size_t)rowA * EDIM + ks * 32 + koffA);
                    haslo = 0;
                    return;
                }
                const uint_t* Hc; int kl;
                if (layer == 0)      { Hc = Hc0 + (size_t)((p - 1) & 1) * HB; kl = ks - 8; }
                else if (ks < 16)    { Hc = Hc0 + (size_t)((p - 1) & 1) * HB; kl = ks; }
                else                 { Hc = Hc1 + (size_t)(p & 1) * HB;       kl = ks - 16; }
                loadH8(Hc + (size_t)rowA * HDIM + kl * 32 + koffA, ah, al);
                haslo = 1;
            };
            // ---- B fragments: LDS if cached, else global (plain, L2-resident) ----
            auto loadB = [&](int i, bf16x8* bh, bf16x8* bl) {
                int ks = ksOf(i);
                if (i < nc) {
                    const ushort_t* p8 = wlds + (size_t)(8 * ks) * 512 + lane * 8;
                    #pragma unroll
                    for (int g = 0; g < 4; ++g) {
                        bh[g] = *(const bf16x8*)(p8 + (size_t)g * 512);
                        bl[g] = *(const bf16x8*)(p8 + (size_t)(4 + g) * 512);
                    }
                } else {
                    const size_t o = bBase + (size_t)ks * 512;
                    #pragma unroll
                    for (int g = 0; g < 4; ++g) {
                        bh[g] = *(const bf16x8*)(Bhi + o + g * gs);
                        bl[g] = *(const bf16x8*)(Blo + o + g * gs);
                    }
                }
            };

            bf16x8 cah, cal, cbh[4], cbl[4]; int chl;
            loadA(ksOf(0), cah, cal, chl);
            loadB(0, cbh, cbl);
            #pragma unroll 2
            for (int i = 0; i < n; ++i) {
                bf16x8 nah = cah, nal = cal, nbh[4], nbl[4]; int nhl = chl;
                #pragma unroll
                for (int g = 0; g < 4; ++g) { nbh[g] = cbh[g]; nbl[g] = cbl[g]; }
                if (i + 1 < n) {
                    loadA(ksOf(i + 1), nah, nal, nhl);
                    loadB(i + 1, nbh, nbl);
                }
                acc0 = MFMA(cah, cbh[0], acc0, 0, 0, 0);
                acc1 = MFMA(cah, cbh[1], acc1, 0, 0, 0);
                acc2 = MFMA(cah, cbh[2], acc2, 0, 0, 0);
                acc3 = MFMA(cah, cbh[3], acc3, 0, 0, 0);
                acc0 = MFMA(cah, cbl[0], acc0, 0, 0, 0);
                acc1 = MFMA(cah, cbl[1], acc1, 0, 0, 0);
                acc2 = MFMA(cah, cbl[2], acc2, 0, 0, 0);
                acc3 = MFMA(cah, cbl[3], acc3, 0, 0, 0);
                if (chl) {
                    acc0 = MFMA(cal, cbh[0], acc0, 0, 0, 0);
                    acc1 = MFMA(cal, cbh[1], acc1, 0, 0, 0);
                    acc2 = MFMA(cal, cbh[2], acc2, 0, 0, 0);
                    acc3 = MFMA(cal, cbh[3], acc3, 0, 0, 0);
                }
                cah = nah; cal = nal; chl = nhl;
                #pragma unroll
                for (int g = 0; g < 4; ++g) { cbh[g] = nbh[g]; cbl[g] = nbl[g]; }
            }

            if (wv == 1) {
                #pragma unroll
                for (int r = 0; r < 4; ++r) {
                    red[0][r][lane] = acc0[r];
                    red[1][r][lane] = acc1[r];
                    red[2][r][lane] = acc2[r];
                    red[3][r][lane] = acc3[r];
                }
            }
        }
        __syncthreads();
        if (active && wv == 0) {
            uint_t* Wc = layer ? (Hc1 + (size_t)((p - 1) & 1) * HB)
                               : (Hc0 + (size_t)(p & 1) * HB);
            #pragma unroll
            for (int r = 0; r < 4; ++r) {
                float gi = acc0[r] + red[0][r][lane] + bg0;
                float gf = acc1[r] + red[1][r][lane] + bg1;
                float gg = acc2[r] + red[2][r][lane] + bg2;
                float go = acc3[r] + red[3][r][lane] + bg3;
                float ig = sigm(gi), fg = sigm(gf), gc = tanh_f(gg), og = sigm(go);
                float cn = fg * cst[r] + ig * gc;
                cst[r] = cn;
                float h = og * tanh_f(cn);
                int b = bt * 16 + (lane >> 4) * 4 + r;
                int cidx = u * 16 + (lane & 15);
                unsigned short hh = f2bf(h);
                float hf = bf2f(hh);
                unsigned short hl = f2bf(h - hf);
                uint_t val = (uint_t)hh | ((uint_t)hl << 16);
                __hip_atomic_store(Wc + (size_t)b * HDIM + cidx, val, __ATOMIC_RELAXED, __HIP_MEMORY_SCOPE_AGENT);
            }
        }
        gridbar(bar, (unsigned)(p + 1));
    }

    // ---------- classifier: out = h1_final @ Wclf^T + bclf ----------
    if (wg == 0 && wv == 0) {
        int b = lane;
        float a0 = bclf[0], a1 = bclf[1];
        const uint_t* hf = Hc1 + HB;   // final h1 in slot 1
        #pragma unroll 8
        for (int k = 0; k < HDIM; ++k) {
            uint_t v = __hip_atomic_load(hf + (size_t)b * HDIM + k, __ATOMIC_RELAXED, __HIP_MEMORY_SCOPE_AGENT);
            float h = bf2f((unsigned short)v) + bf2f((unsigned short)(v >> 16));
            a0 = fmaf(h, Wclf[k], a0);
            a1 = fmaf(h, Wclf[HDIM + k], a1);
        }
        out[b * 2 + 0] = a0;
        out[b * 2 + 1] = a1;
    }
}

extern "C" void kernel_launch(void* const* d_in, const int* in_sizes, int n_in,
                              void* d_out, int out_size, void* d_ws, size_t ws_size,
                              hipStream_t stream) {
    const int*   x     = (const int*)d_in[0];
    const float* emb   = (const float*)d_in[1];
    const float* Wih0  = (const float*)d_in[2];
    const float* Whh0  = (const float*)d_in[3];
    const float* bias0 = (const float*)d_in[4];
    const float* Wih1  = (const float*)d_in[5];
    const float* Whh1  = (const float*)d_in[6];
    const float* bias1 = (const float*)d_in[7];
    const float* Wclf  = (const float*)d_in[8];
    const float* bclf  = (const float*)d_in[9];
    float* out = (float*)d_out;

    char* base = (char*)d_ws;
    ushort_t* XeHi = (ushort_t*)(base + BYTE_XEHI);
    uint_t*   Hc0  = (uint_t*)(base + BYTE_HC0);
    uint_t*   Hc1  = (uint_t*)(base + BYTE_HC1);
    uint_t*   bar  = (uint_t*)(base + BYTE_BAR);
    ushort_t* B0hi = (ushort_t*)(base + BYTE_B0HI);
    ushort_t* B0lo = (ushort_t*)(base + BYTE_B0LO);
    ushort_t* B1hi = (ushort_t*)(base + BYTE_B1HI);
    ushort_t* B1lo = (ushort_t*)(base + BYTE_B1LO);

    // 1) gather+convert embeddings
    xepack_kernel<<<4096, 256, 0, stream>>>(x, emb, XeHi);
    // 2) pack weights (hi/lo) to fragment order
    wpack_kernel<<<1793, 256, 0, stream>>>(Wih0, Whh0, Wih1, Whh1, B0hi, B0lo, B1hi, B1lo);
    // 3) zero h-state (4*HB uints) and barrier area (1024 uints)
    zero_kernel<<<512, 256, 0, stream>>>(Hc0, 4 * HB);
    zero_kernel<<<4, 256, 0, stream>>>(bar, 1024);
    // 4) persistent cooperative LSTM
    void* args[] = {
        (void*)&XeHi, (void*)&Hc0, (void*)&Hc1, (void*)&bar,
        (void*)&B0hi, (void*)&B0lo, (void*)&B1hi, (void*)&B1lo,
        (void*)&bias0, (void*)&bias1,
        (void*)&Wclf, (void*)&bclf,
        (void*)&out
    };
    hipLaunchCooperativeKernel((void*)lstm_main, dim3(NWG), dim3(128), args, 0, stream);
}